// Round 6
// baseline (393.717 us; speedup 1.0000x reference)
//
#include <hip/hip_runtime.h>
#include <hip/hip_fp16.h>

// LSTM: B=256, T=1024, I=64, H=25 (4H=100), O=64. fp32 in/out.
//
// R6 theory: rec8 (563 cy/step, VALUBusy 18%) is ISSUE-bound on a single
//   wave (1 wave/SIMD = 1 VALU inst per 2 cy): f32x2 ops scalarize and the
//   readlane->hv broadcast adds movs -> ~200+ inst/step. Memory theories
//   (R4 alias, R5 store-WAW) both measured dead. Fixes:
//   (1) wave-specialization: 128-thr blocks; wave0 = recurrence only,
//       wave1 (different SIMD, free issue slots) = FC + out stores, fed
//       via a 16-slot LDS h-ring, raw s_barrier every 8 steps (lgkmcnt
//       only -- NOT __syncthreads, which drains the load ring's vmcnt).
//   (2) dots via per-j SGPR broadcast: readlane(h,j) + v_fmac x2 gates
//       (25 rl + 50 fma, deterministic; no packing, no movs), 2-acc parity.
//   (3) k1 epilogue: per-wave 16x20 LDS transpose tile -> dwordx4 stores
//       (was 4-row-strided scalar dword scatter; k1 ran 5x its roofline).
// Carried: gate split across wave halves, exp2 scale folding, (i,g)/(f,o)
//   gws layout (one dwordx2/lane/step), 8-deep ring, xswap returning b
//   (validated R4), hoisted W-prep kernel.

#define Bn 256
#define Tn 1024
#define In 64
#define Hn 25
#define Gn 100
#define On 64
#define BT (Bn * Tn)
#define ROW 100

#define SCL_S -1.44269504089f   // -log2(e)   : sigmoid gates (i,f,o)
#define SCL_T -2.88539008178f   // -2*log2(e) : tanh gate (g)

typedef __attribute__((ext_vector_type(8))) short short8;
typedef __attribute__((ext_vector_type(4))) float f32x4;
typedef __attribute__((ext_vector_type(2))) float f32x2;

__device__ __forceinline__ float frcp(float x) { return __builtin_amdgcn_rcpf(x); }
__device__ __forceinline__ float ex2(float x) {
    float r;
    asm("v_exp_f32 %0, %1\n\ts_nop 1" : "=v"(r) : "v"(x));
    return r;
}
__device__ __forceinline__ float bcast(float v, int lane) {
    return __int_as_float(__builtin_amdgcn_readlane(__float_as_int(v), lane));
}
__device__ __forceinline__ float xswap(float x) {
    // returned b's LOW lanes hold the high-half value (validated R4).
    float a = x, b = x;
    asm("s_nop 0\n\tv_permlane32_swap_b32 %0, %1\n\ts_nop 0"
        : "+v"(a), "+v"(b));
    return b;
}
__device__ __forceinline__ short f2bf(float f) {   // RNE fp32 -> bf16 bits
    unsigned u = __float_as_uint(f);
    unsigned r = (u + 0x7FFFu + ((u >> 16) & 1u)) >> 16;
    return (short)r;
}

// gws column map: n<50: unit n>>1, gate i (even) / g (odd);
//                 n>=50: m=n-50, unit m>>1, gate f (even) / o (odd).
__device__ __forceinline__ void colmap(int n, int& g, float& scl) {
    if (n < 50) {
        const int r = n >> 1;
        g = ((n & 1) ? 2 : 0) * Hn + r;
        scl = (n & 1) ? SCL_T : SCL_S;
    } else {
        const int m = n - 50, r = m >> 1;
        g = ((m & 1) ? 3 : 1) * Hn + r;
        scl = SCL_S;
    }
}

// ---------------- kernel 0: one-time W/bias prep (14.8 KB in ws tail) ----
__global__ __launch_bounds__(256)
void prep_w(const float* __restrict__ W_ih, const float* __restrict__ b_ih,
            const float* __restrict__ b_hh, short* __restrict__ wprep,
            float* __restrict__ bprep) {
    const int tid = threadIdx.x;
    for (int i = tid; i < 112 * 64; i += 256) {
        const int n = i >> 6, k = i & 63;
        float v = 0.f;
        if (n < Gn) {
            int g; float scl;
            colmap(n, g, scl);
            v = W_ih[(size_t)g * In + k] * scl;
        }
        wprep[i] = f2bf(v);
    }
    if (tid < 112) {
        float v = 0.f;
        if (tid < Gn) {
            int g; float scl;
            colmap(tid, g, scl);
            v = (b_ih[g] + b_hh[g]) * scl;
        }
        bprep[tid] = v;
    }
}

// ---------------- kernel 1: input GEMM via MFMA ----------------
template <typename ST, bool PREP>
__global__ __launch_bounds__(256, 4)
void gates_mfma(const float* __restrict__ x, const float* __restrict__ W_ih,
                const float* __restrict__ b_ih, const float* __restrict__ b_hh,
                const short* __restrict__ wprep, const float* __restrict__ bprep,
                ST* __restrict__ gws) {
    __shared__ short lA[64 * 72];
    __shared__ short lB[112 * 72];
    __shared__ float lbias[112];
    __shared__ __align__(16) float swz[4][16][20];   // per-wave transpose tile

    const int tid = threadIdx.x;
    const size_t row0 = (size_t)blockIdx.x * 64;

    for (int i = tid; i < 64 * 64; i += 256) {
        const int r = i >> 6, k = i & 63;
        lA[r * 72 + k] = f2bf(x[(row0 + r) * In + k]);
    }
    if (PREP) {
        for (int i = tid; i < 112 * 32; i += 256) {
            const int j = 2 * i, n = j >> 6, k = j & 63;
            *(int*)&lB[n * 72 + k] = ((const int*)wprep)[i];
        }
        if (tid < 112) lbias[tid] = bprep[tid];
    } else {
        for (int i = tid; i < 112 * 64; i += 256) {
            const int n = i >> 6, k = i & 63;
            float v = 0.f;
            if (n < Gn) {
                int g; float scl;
                colmap(n, g, scl);
                v = W_ih[(size_t)g * In + k] * scl;
            }
            lB[n * 72 + k] = f2bf(v);
        }
        if (tid < 112) {
            float v = 0.f;
            if (tid < Gn) {
                int g; float scl;
                colmap(tid, g, scl);
                v = (b_ih[g] + b_hh[g]) * scl;
            }
            lbias[tid] = v;
        }
    }
    __syncthreads();

    const int wave = tid >> 6;
    const int lane = tid & 63;
    const int quad = lane >> 4;
    const int l16  = lane & 15;
    const int arow = wave * 16 + l16;

    const short8 a0 = *(const short8*)&lA[arow * 72 + 0  + quad * 8];
    const short8 a1 = *(const short8*)&lA[arow * 72 + 32 + quad * 8];

    float* tw = &swz[wave][0][0];
    const int rr2 = lane >> 2;
    const int c4  = (lane & 3) * 4;

#pragma unroll
    for (int nt = 0; nt < 7; ++nt) {
        const int col = nt * 16 + l16;
        const short8 b0 = *(const short8*)&lB[col * 72 + 0  + quad * 8];
        const short8 b1 = *(const short8*)&lB[col * 72 + 32 + quad * 8];
        const float bias = (col < Gn) ? lbias[col] : 0.f;
        f32x4 acc = {bias, bias, bias, bias};
        acc = __builtin_amdgcn_mfma_f32_16x16x32_bf16(a0, b0, acc, 0, 0, 0);
        acc = __builtin_amdgcn_mfma_f32_16x16x32_bf16(a1, b1, acc, 0, 0, 0);

        if constexpr (sizeof(ST) == 4) {
            // transpose in per-wave LDS tile, store dwordx4 (coalesced-ish,
            // 4x fewer VMEM ops than the 4-row scalar scatter)
#pragma unroll
            for (int i = 0; i < 4; ++i) tw[(quad * 4 + i) * 20 + l16] = acc[i];
            asm volatile("s_waitcnt lgkmcnt(0)" ::: "memory");
            const f32x4 v = *(const f32x4*)&tw[rr2 * 20 + c4];
            const int col2 = nt * 16 + c4;
            if (col2 < Gn) {
                const size_t grow2 = row0 + wave * 16 + rr2;
                *(f32x4*)&((float*)gws)[grow2 * ROW + col2] = v;
            }
            asm volatile("s_waitcnt lgkmcnt(0)" ::: "memory"); // WAR on tile
        } else {
            if (col < Gn) {
#pragma unroll
                for (int i = 0; i < 4; ++i) {
                    const size_t grow = row0 + wave * 16 + quad * 4 + i;
                    gws[grow * ROW + col] = (ST)acc[i];
                }
            }
        }
    }
}

// ---------------- kernel 2: recurrence (wave0) + FC (wave1) --------------
template <typename ST> struct G2;
template <> struct G2<float> {
    static __device__ __forceinline__ float2 ld(const float* p) {
        return *(const float2*)p;
    }
};
template <> struct G2<__half> {
    static __device__ __forceinline__ float2 ld(const __half* p) {
        ushort2 u = *(const ushort2*)p;
        __half a, b;
        *(unsigned short*)&a = u.x; *(unsigned short*)&b = u.y;
        return make_float2((float)a, (float)b);
    }
};

template <typename ST>
__global__ __launch_bounds__(128, 1)
void lstm_rec9(const ST* __restrict__ gws, const float* __restrict__ W_hh,
               const float* __restrict__ W_fc, const float* __restrict__ b_fc,
               float* __restrict__ out) {
    __shared__ float hbuf[16][64];   // 16-slot h ring (cols 25..63 junk)

    const int tid  = threadIdx.x;
    const int wid  = tid >> 6;
    const int lane = tid & 63;
    const int b    = blockIdx.x;

    // ---- per-wave state (liveness is per-path; 1 block/CU so no pressure)
    float wAv[25], wBv[25];          // wave0: recurrent weights
    float2 ring[8];                  // wave0: gate prefetch ring
    float c = 0.f, h = 0.f;          // wave0: state
    float sB = 1.f, dB = 0.f;        // wave0: tanh/sigmoid affine
    const ST* gp = nullptr;          // wave0: gate pointer
    float wFC[25];                   // wave1: FC weights
    float bfc = 0.f;                 // wave1: FC bias
    float* op = nullptr;             // wave1: out pointer

    if (wid == 0) {
        const bool lo = lane < 32;
        const int rr  = min(lane & 31, Hn - 1);
        const float sclA = SCL_S;
        const float sclB = lo ? SCL_T : SCL_S;
        sB = lo ? 2.f : 1.f;
        dB = lo ? -1.f : 0.f;
        const float* rowA = W_hh + (size_t)((lo ? 0 : 1) * Hn + rr) * Hn;
        const float* rowB = W_hh + (size_t)((lo ? 2 : 3) * Hn + rr) * Hn;
#pragma unroll
        for (int j = 0; j < 25; ++j) {
            wAv[j] = rowA[j] * sclA;
            wBv[j] = rowB[j] * sclB;
        }
        const int coff = 2 * rr + (lo ? 0 : 50);
        gp = gws + (size_t)b * Tn * ROW + coff;
#pragma unroll
        for (int s = 0; s < 8; ++s) ring[s] = G2<ST>::ld(gp + (size_t)s * ROW);
    } else {
#pragma unroll
        for (int j = 0; j < 25; ++j) wFC[j] = W_fc[(size_t)lane * Hn + j];
        bfc = b_fc[lane];
        op = out + (size_t)b * Tn * On + lane;
    }

#pragma unroll 1
    for (int k = 0; k < 129; ++k) {
        if (wid == 0) {
            if (k < 128) {
#pragma unroll
                for (int s = 0; s < 8; ++s) {
                    const int t = k * 8 + s;
                    int tp = t + 8; if (tp > Tn - 1) tp = Tn - 1;
                    const float2 nxt = G2<ST>::ld(gp + (size_t)tp * ROW);

                    // gates: SGPR-broadcast fmac, 2-acc parity (chain ~13 fma)
                    float aA0 = ring[s].x, aB0 = ring[s].y;
                    float aA1 = 0.f,       aB1 = 0.f;
#pragma unroll
                    for (int j = 0; j < 24; j += 2) {
                        const float h0 = bcast(h, j);
                        const float h1 = bcast(h, j + 1);
                        aA0 = fmaf(wAv[j],     h0, aA0);
                        aB0 = fmaf(wBv[j],     h0, aB0);
                        aA1 = fmaf(wAv[j + 1], h1, aA1);
                        aB1 = fmaf(wBv[j + 1], h1, aB1);
                    }
                    {
                        const float h0 = bcast(h, 24);
                        aA0 = fmaf(wAv[24], h0, aA0);
                        aB0 = fmaf(wBv[24], h0, aB0);
                    }
                    const float aA = aA0 + aA1;
                    const float aB = aB0 + aB1;
                    ring[s] = nxt;

                    const float actA = frcp(1.f + ex2(aA));            // I / F
                    const float actB = sB * frcp(1.f + ex2(aB)) + dB;  // G / O
                    const float Fg = xswap(actA);
                    const float Og = xswap(actB);
                    c = Fg * c + actA * actB;                // valid lanes 0..24
                    const float th = 2.f * frcp(1.f + ex2(c * SCL_T)) - 1.f;
                    h = Og * th;

                    hbuf[t & 15][lane] = h;                  // junk in lanes 25+
                }
            }
        } else {
            if (k >= 1) {
#pragma unroll
                for (int s = 0; s < 8; ++s) {
                    const int t = (k - 1) * 8 + s;
                    float a0 = bfc, a1 = 0.f;
#pragma unroll
                    for (int j = 0; j < 24; j += 2) {
                        a0 = fmaf(hbuf[t & 15][j],     wFC[j],     a0);
                        a1 = fmaf(hbuf[t & 15][j + 1], wFC[j + 1], a1);
                    }
                    a0 = fmaf(hbuf[t & 15][24], wFC[24], a0);
                    op[(size_t)t * On] = a0 + a1;
                }
            }
        }
        // raw barrier: LDS drain only -- keep wave0's global loads in flight
        asm volatile("s_waitcnt lgkmcnt(0)" ::: "memory");
        __builtin_amdgcn_s_barrier();
        asm volatile("" ::: "memory");
    }
}

extern "C" void kernel_launch(void* const* d_in, const int* in_sizes, int n_in,
                              void* d_out, int out_size, void* d_ws, size_t ws_size,
                              hipStream_t stream) {
    const float* x    = (const float*)d_in[0];
    const float* W_ih = (const float*)d_in[1];
    const float* W_hh = (const float*)d_in[2];
    const float* b_ih = (const float*)d_in[3];
    const float* b_hh = (const float*)d_in[4];
    const float* W_fc = (const float*)d_in[5];
    const float* b_fc = (const float*)d_in[6];
    float* out = (float*)d_out;

    const size_t need_f32 = (size_t)BT * ROW * sizeof(float);   // 104.9 MB
    const size_t need_h   = (size_t)BT * ROW * sizeof(__half);  //  52.4 MB
    const size_t PREPB    = 16384;                              // W(14336)+b(448)
    const int nb1 = BT / 64;                                    // 4096

    if (ws_size >= need_f32) {
        float* gws = (float*)d_ws;
        if (ws_size >= need_f32 + PREPB) {
            short* wprep = (short*)((char*)d_ws + need_f32);
            float* bprep = (float*)(wprep + 112 * 64);
            prep_w<<<1, 256, 0, stream>>>(W_ih, b_ih, b_hh, wprep, bprep);
            gates_mfma<float, true><<<nb1, 256, 0, stream>>>(
                x, W_ih, b_ih, b_hh, wprep, bprep, gws);
        } else {
            gates_mfma<float, false><<<nb1, 256, 0, stream>>>(
                x, W_ih, b_ih, b_hh, nullptr, nullptr, gws);
        }
        lstm_rec9<float><<<Bn, 128, 0, stream>>>(gws, W_hh, W_fc, b_fc, out);
    } else {
        __half* gws = (__half*)d_ws;
        if (ws_size >= need_h + PREPB) {
            short* wprep = (short*)((char*)d_ws + need_h);
            float* bprep = (float*)(wprep + 112 * 64);
            prep_w<<<1, 256, 0, stream>>>(W_ih, b_ih, b_hh, wprep, bprep);
            gates_mfma<__half, true><<<nb1, 256, 0, stream>>>(
                x, W_ih, b_ih, b_hh, wprep, bprep, gws);
        } else {
            gates_mfma<__half, false><<<nb1, 256, 0, stream>>>(
                x, W_ih, b_ih, b_hh, nullptr, nullptr, gws);
        }
        lstm_rec9<__half><<<Bn, 128, 0, stream>>>(gws, W_hh, W_fc, b_fc, out);
    }
}

// Round 7
// 360.067 us; speedup vs baseline: 1.0935x; 1.0935x over previous
//
#include <hip/hip_runtime.h>
#include <hip/hip_fp16.h>

// LSTM: B=256, T=1024, I=64, H=25 (4H=100), O=64. fp32 in/out.
//
// R7 theory: rec6..rec9 all ~530-570 cy/step despite different compute
//   structures -> the invariant is a per-step GLOBAL gate load whose
//   latency the compiler exposes (it re-clusters the unrolled ring loads /
//   places a conservative waitcnt): exposed ~(L2 200 + HBM 900)/2 = 550 cy
//   matches 566 measured. Compute (~225 cy issue) hides under it, which is
//   why R4/R5/R6 compute fixes were all neutral.
// rec10: wave0 NEVER touches global memory.
//   wave1 = gate producer (chunk k+1: 8 rows x 100 f32 CONTIGUOUS in gws,
//   global->LDS gbuf[2][800], double-buffered, 1 chunk ahead)
//   + FC consumer (chunk k-1 from hbuf) + out stores.
//   wave0 = recurrence only: 8x ds_read_b64/chunk (compiler lgkmcnt),
//   dot/activations, h -> hbuf. Barrier per chunk (129 total; measured
//   cheap in R6). k1 reverted to R5 epilogue (R6 transpose was neutral).
// Carried: gate split across wave halves, exp2 scale folding, (i,g)/(f,o)
//   gws layout, xswap via permlane32_swap returning b (validated R4),
//   SGPR-broadcast fmac dots, hoisted W-prep kernel.

#define Bn 256
#define Tn 1024
#define In 64
#define Hn 25
#define Gn 100
#define On 64
#define BT (Bn * Tn)
#define ROW 100

#define SCL_S -1.44269504089f   // -log2(e)   : sigmoid gates (i,f,o)
#define SCL_T -2.88539008178f   // -2*log2(e) : tanh gate (g)

typedef __attribute__((ext_vector_type(8))) short short8;
typedef __attribute__((ext_vector_type(4))) float f32x4;

__device__ __forceinline__ float frcp(float x) { return __builtin_amdgcn_rcpf(x); }
__device__ __forceinline__ float ex2(float x) {
    float r;
    asm("v_exp_f32 %0, %1\n\ts_nop 1" : "=v"(r) : "v"(x));
    return r;
}
__device__ __forceinline__ float bcast(float v, int lane) {
    return __int_as_float(__builtin_amdgcn_readlane(__float_as_int(v), lane));
}
__device__ __forceinline__ float xswap(float x) {
    // returned b's LOW lanes hold the high-half value (validated R4).
    float a = x, b = x;
    asm("s_nop 0\n\tv_permlane32_swap_b32 %0, %1\n\ts_nop 0"
        : "+v"(a), "+v"(b));
    return b;
}
__device__ __forceinline__ short f2bf(float f) {   // RNE fp32 -> bf16 bits
    unsigned u = __float_as_uint(f);
    unsigned r = (u + 0x7FFFu + ((u >> 16) & 1u)) >> 16;
    return (short)r;
}

// gws column map: n<50: unit n>>1, gate i (even) / g (odd);
//                 n>=50: m=n-50, unit m>>1, gate f (even) / o (odd).
__device__ __forceinline__ void colmap(int n, int& g, float& scl) {
    if (n < 50) {
        const int r = n >> 1;
        g = ((n & 1) ? 2 : 0) * Hn + r;
        scl = (n & 1) ? SCL_T : SCL_S;
    } else {
        const int m = n - 50, r = m >> 1;
        g = ((m & 1) ? 3 : 1) * Hn + r;
        scl = SCL_S;
    }
}

// ---------------- kernel 0: one-time W/bias prep (14.8 KB in ws tail) ----
__global__ __launch_bounds__(256)
void prep_w(const float* __restrict__ W_ih, const float* __restrict__ b_ih,
            const float* __restrict__ b_hh, short* __restrict__ wprep,
            float* __restrict__ bprep) {
    const int tid = threadIdx.x;
    for (int i = tid; i < 112 * 64; i += 256) {
        const int n = i >> 6, k = i & 63;
        float v = 0.f;
        if (n < Gn) {
            int g; float scl;
            colmap(n, g, scl);
            v = W_ih[(size_t)g * In + k] * scl;
        }
        wprep[i] = f2bf(v);
    }
    if (tid < 112) {
        float v = 0.f;
        if (tid < Gn) {
            int g; float scl;
            colmap(tid, g, scl);
            v = (b_ih[g] + b_hh[g]) * scl;
        }
        bprep[tid] = v;
    }
}

// ---------------- kernel 1: input GEMM via MFMA ----------------
template <typename ST, bool PREP>
__global__ __launch_bounds__(256, 4)
void gates_mfma(const float* __restrict__ x, const float* __restrict__ W_ih,
                const float* __restrict__ b_ih, const float* __restrict__ b_hh,
                const short* __restrict__ wprep, const float* __restrict__ bprep,
                ST* __restrict__ gws) {
    __shared__ short lA[64 * 72];
    __shared__ short lB[112 * 72];
    __shared__ float lbias[112];

    const int tid = threadIdx.x;
    const size_t row0 = (size_t)blockIdx.x * 64;

    for (int i = tid; i < 64 * 64; i += 256) {
        const int r = i >> 6, k = i & 63;
        lA[r * 72 + k] = f2bf(x[(row0 + r) * In + k]);
    }
    if (PREP) {
        for (int i = tid; i < 112 * 32; i += 256) {
            const int j = 2 * i, n = j >> 6, k = j & 63;
            *(int*)&lB[n * 72 + k] = ((const int*)wprep)[i];
        }
        if (tid < 112) lbias[tid] = bprep[tid];
    } else {
        for (int i = tid; i < 112 * 64; i += 256) {
            const int n = i >> 6, k = i & 63;
            float v = 0.f;
            if (n < Gn) {
                int g; float scl;
                colmap(n, g, scl);
                v = W_ih[(size_t)g * In + k] * scl;
            }
            lB[n * 72 + k] = f2bf(v);
        }
        if (tid < 112) {
            float v = 0.f;
            if (tid < Gn) {
                int g; float scl;
                colmap(tid, g, scl);
                v = (b_ih[g] + b_hh[g]) * scl;
            }
            lbias[tid] = v;
        }
    }
    __syncthreads();

    const int wave = tid >> 6;
    const int lane = tid & 63;
    const int quad = lane >> 4;
    const int l16  = lane & 15;
    const int arow = wave * 16 + l16;

    const short8 a0 = *(const short8*)&lA[arow * 72 + 0  + quad * 8];
    const short8 a1 = *(const short8*)&lA[arow * 72 + 32 + quad * 8];

#pragma unroll
    for (int nt = 0; nt < 7; ++nt) {
        const int col = nt * 16 + l16;
        const short8 b0 = *(const short8*)&lB[col * 72 + 0  + quad * 8];
        const short8 b1 = *(const short8*)&lB[col * 72 + 32 + quad * 8];
        const float bias = lbias[col];
        f32x4 acc = {bias, bias, bias, bias};
        acc = __builtin_amdgcn_mfma_f32_16x16x32_bf16(a0, b0, acc, 0, 0, 0);
        acc = __builtin_amdgcn_mfma_f32_16x16x32_bf16(a1, b1, acc, 0, 0, 0);
        if (col < Gn) {
#pragma unroll
            for (int i = 0; i < 4; ++i) {
                const size_t grow = row0 + wave * 16 + quad * 4 + i;
                gws[grow * ROW + col] = (ST)acc[i];
            }
        }
    }
}

// ---------------- kernel 2: wave0 = recurrence (LDS only),
//                  wave1 = gate producer + FC + out stores ---------------
template <typename ST> struct GLD;   // 2 gws elements -> float2
template <> struct GLD<float> {
    static __device__ __forceinline__ float2 ld(const float* base, int u) {
        return ((const float2*)base)[u];
    }
};
template <> struct GLD<__half> {
    static __device__ __forceinline__ float2 ld(const __half* base, int u) {
        const __half2 h = ((const __half2*)base)[u];
        return make_float2(__low2float(h), __high2float(h));
    }
};

template <typename ST>
__global__ __launch_bounds__(128, 1)
void lstm_rec10(const ST* __restrict__ gws, const float* __restrict__ W_hh,
                const float* __restrict__ W_fc, const float* __restrict__ b_fc,
                float* __restrict__ out) {
    __shared__ float gbuf[2][800];   // 2 x (8 rows x 100 gates), double-buffered
    __shared__ float hbuf[16][64];   // 16-slot h ring (cols 25..63 junk)

    const int tid  = threadIdx.x;
    const int wid  = tid >> 6;
    const int lane = tid & 63;
    const int b    = blockIdx.x;

    float wAv[25], wBv[25];          // wave0: recurrent weights
    float c = 0.f, h = 0.f;          // wave0: state
    float sB = 1.f, dB = 0.f;
    int coff = 0;
    float wFC[25];                   // wave1: FC weights
    float bfc = 0.f;
    float* op = nullptr;
    const ST* src = gws + (size_t)b * Tn * ROW;   // chunk c at +c*800 elements

    if (wid == 0) {
        const bool lo = lane < 32;
        const int rr  = min(lane & 31, Hn - 1);
        const float sclA = SCL_S;
        const float sclB = lo ? SCL_T : SCL_S;
        sB = lo ? 2.f : 1.f;
        dB = lo ? -1.f : 0.f;
        const float* rowA = W_hh + (size_t)((lo ? 0 : 1) * Hn + rr) * Hn;
        const float* rowB = W_hh + (size_t)((lo ? 2 : 3) * Hn + rr) * Hn;
#pragma unroll
        for (int j = 0; j < 25; ++j) {
            wAv[j] = rowA[j] * sclA;
            wBv[j] = rowB[j] * sclB;
        }
        coff = 2 * rr + (lo ? 0 : 50);
    } else {
#pragma unroll
        for (int j = 0; j < 25; ++j) wFC[j] = W_fc[(size_t)lane * Hn + j];
        bfc = b_fc[lane];
        op = out + (size_t)b * Tn * On + lane;

        // prologue: stage chunk 0 into gbuf[0]
        float2 t0[6]; float2 t6;
#pragma unroll
        for (int i = 0; i < 6; ++i) t0[i] = GLD<ST>::ld(src, lane + 64 * i);
        if (lane < 16) t6 = GLD<ST>::ld(src, 384 + lane);
#pragma unroll
        for (int i = 0; i < 6; ++i)
            *(float2*)&gbuf[0][2 * (lane + 64 * i)] = t0[i];
        if (lane < 16) *(float2*)&gbuf[0][2 * (384 + lane)] = t6;
    }
    asm volatile("s_waitcnt lgkmcnt(0)" ::: "memory");
    __builtin_amdgcn_s_barrier();
    asm volatile("" ::: "memory");

#pragma unroll 1
    for (int k = 0; k < 129; ++k) {
        if (wid == 0) {
            if (k < 128) {
                const int kb = k & 1;
                float2 g[8];
#pragma unroll
                for (int s = 0; s < 8; ++s)
                    g[s] = *(const float2*)&gbuf[kb][s * 100 + coff];
#pragma unroll
                for (int s = 0; s < 8; ++s) {
                    const int t = k * 8 + s;
                    float aA0 = g[s].x, aB0 = g[s].y;
                    float aA1 = 0.f,   aB1 = 0.f;
#pragma unroll
                    for (int j = 0; j < 24; j += 2) {
                        const float h0 = bcast(h, j);
                        const float h1 = bcast(h, j + 1);
                        aA0 = fmaf(wAv[j],     h0, aA0);
                        aB0 = fmaf(wBv[j],     h0, aB0);
                        aA1 = fmaf(wAv[j + 1], h1, aA1);
                        aB1 = fmaf(wBv[j + 1], h1, aB1);
                    }
                    {
                        const float h0 = bcast(h, 24);
                        aA0 = fmaf(wAv[24], h0, aA0);
                        aB0 = fmaf(wBv[24], h0, aB0);
                    }
                    const float aA = aA0 + aA1;
                    const float aB = aB0 + aB1;

                    const float actA = frcp(1.f + ex2(aA));            // I / F
                    const float actB = sB * frcp(1.f + ex2(aB)) + dB;  // G / O
                    const float Fg = xswap(actA);
                    const float Og = xswap(actB);
                    c = Fg * c + actA * actB;                // valid lanes 0..24
                    const float th = 2.f * frcp(1.f + ex2(c * SCL_T)) - 1.f;
                    h = Og * th;

                    hbuf[t & 15][lane] = h;                  // junk in lanes 25+
                }
            }
        } else {
            // stage chunk k+1 into gbuf[(k+1)&1] (loads issued first, writes
            // after FC -> HBM latency hides under the FC work + wave0 slack)
            float2 t0[6]; float2 t6;
            if (k < 127) {
                const ST* s1 = src + (size_t)(k + 1) * 800;
#pragma unroll
                for (int i = 0; i < 6; ++i) t0[i] = GLD<ST>::ld(s1, lane + 64 * i);
                if (lane < 16) t6 = GLD<ST>::ld(s1, 384 + lane);
            }
            if (k >= 1) {
                // FC for chunk k-1 (hbuf slots of opposite parity)
#pragma unroll
                for (int s = 0; s < 8; ++s) {
                    const int t = (k - 1) * 8 + s;
                    const int sl = t & 15;
                    float a0 = bfc, a1 = 0.f;
#pragma unroll
                    for (int j = 0; j < 24; j += 2) {
                        a0 = fmaf(hbuf[sl][j],     wFC[j],     a0);
                        a1 = fmaf(hbuf[sl][j + 1], wFC[j + 1], a1);
                    }
                    a0 = fmaf(hbuf[sl][24], wFC[24], a0);
                    op[(size_t)t * On] = a0 + a1;
                }
            }
            if (k < 127) {
                const int nb = (k + 1) & 1;
#pragma unroll
                for (int i = 0; i < 6; ++i)
                    *(float2*)&gbuf[nb][2 * (lane + 64 * i)] = t0[i];
                if (lane < 16) *(float2*)&gbuf[nb][2 * (384 + lane)] = t6;
            }
        }
        // raw barrier: drain LDS only (no global/vmcnt coupling for wave0)
        asm volatile("s_waitcnt lgkmcnt(0)" ::: "memory");
        __builtin_amdgcn_s_barrier();
        asm volatile("" ::: "memory");
    }
}

extern "C" void kernel_launch(void* const* d_in, const int* in_sizes, int n_in,
                              void* d_out, int out_size, void* d_ws, size_t ws_size,
                              hipStream_t stream) {
    const float* x    = (const float*)d_in[0];
    const float* W_ih = (const float*)d_in[1];
    const float* W_hh = (const float*)d_in[2];
    const float* b_ih = (const float*)d_in[3];
    const float* b_hh = (const float*)d_in[4];
    const float* W_fc = (const float*)d_in[5];
    const float* b_fc = (const float*)d_in[6];
    float* out = (float*)d_out;

    const size_t need_f32 = (size_t)BT * ROW * sizeof(float);   // 104.9 MB
    const size_t need_h   = (size_t)BT * ROW * sizeof(__half);  //  52.4 MB
    const size_t PREPB    = 16384;                              // W(14336)+b(448)
    const int nb1 = BT / 64;                                    // 4096

    if (ws_size >= need_f32) {
        float* gws = (float*)d_ws;
        if (ws_size >= need_f32 + PREPB) {
            short* wprep = (short*)((char*)d_ws + need_f32);
            float* bprep = (float*)(wprep + 112 * 64);
            prep_w<<<1, 256, 0, stream>>>(W_ih, b_ih, b_hh, wprep, bprep);
            gates_mfma<float, true><<<nb1, 256, 0, stream>>>(
                x, W_ih, b_ih, b_hh, wprep, bprep, gws);
        } else {
            gates_mfma<float, false><<<nb1, 256, 0, stream>>>(
                x, W_ih, b_ih, b_hh, nullptr, nullptr, gws);
        }
        lstm_rec10<float><<<Bn, 128, 0, stream>>>(gws, W_hh, W_fc, b_fc, out);
    } else {
        __half* gws = (__half*)d_ws;
        if (ws_size >= need_h + PREPB) {
            short* wprep = (short*)((char*)d_ws + need_h);
            float* bprep = (float*)(wprep + 112 * 64);
            prep_w<<<1, 256, 0, stream>>>(W_ih, b_ih, b_hh, wprep, bprep);
            gates_mfma<__half, true><<<nb1, 256, 0, stream>>>(
                x, W_ih, b_ih, b_hh, wprep, bprep, gws);
        } else {
            gates_mfma<__half, false><<<nb1, 256, 0, stream>>>(
                x, W_ih, b_ih, b_hh, nullptr, nullptr, gws);
        }
        lstm_rec10<__half><<<Bn, 128, 0, stream>>>(gws, W_hh, W_fc, b_fc, out);
    }
}

// Round 9
// 310.506 us; speedup vs baseline: 1.2680x; 1.1596x over previous
//
#include <hip/hip_runtime.h>
#include <hip/hip_fp16.h>

// LSTM: B=256, T=1024, I=64, H=25 (4H=100), O=64. fp32 in/out.
//
// R9 = R8 resubmission (container failure audited: no OOB, no barrier
//   divergence, no watchdog risk -> infra flake suspected, like R1).
//   Defensive change: prologue handoff uses __syncthreads() (full drain,
//   one-time) instead of raw s_barrier; main loop keeps the R6/R7-proven
//   raw s_barrier + lgkmcnt(0) pattern.
//
// R8 design: FUSE the input GEMM into the recurrence kernel -> ONE kernel.
//   Evidence: k1+prep ~145us in EVERY round (R3/R5/R7 subtraction), 5x its
//   ~30us roofline; two k1 micro-fixes (R5 prep hoist, R6 epilogue) were
//   neutral -> structural cost (4096-block launch + 105MB gws write + 105MB
//   re-read). k2's chunk loop (211us) is the serial floor; k1 is overhead
//   stacked on top. Fix: 3 waves per block (192 thr), 1 block per batch:
//     wave0 = recurrence (UNCHANGED from validated rec10)
//     wave1 = FC + out stores
//     wave2 = gate producer: x chunk (2KB contiguous) -> bf16 -> LDS ->
//             k1's exact MFMA fragment pattern (A 16 rows / 8 valid,
//             B resident in 56 VGPRs) -> gbuf[(k+1)&1] with bias.
//   x loads issued 1 chunk (~2000cy) ahead -> latency fully hidden; wave2
//   (~600cy/chunk) fits in wave0's (~2400cy) shadow. Deletes gws entirely
//   (-210MB HBM round trip), prep_w, and 2 kernel launches. ws unused.
// Carried: gate split across wave halves, exp2 scale folding, (i,g)/(f,o)
//   gate layout, xswap via permlane32_swap returning b (validated R4),
//   SGPR-broadcast fmac dots, LDS h-ring to FC wave.

#define Bn 256
#define Tn 1024
#define In 64
#define Hn 25
#define Gn 100
#define On 64

#define SCL_S -1.44269504089f   // -log2(e)   : sigmoid gates (i,f,o)
#define SCL_T -2.88539008178f   // -2*log2(e) : tanh gate (g)

typedef __attribute__((ext_vector_type(8))) short short8;
typedef __attribute__((ext_vector_type(4))) float f32x4;
typedef __attribute__((ext_vector_type(4))) int i32x4;

__device__ __forceinline__ float frcp(float x) { return __builtin_amdgcn_rcpf(x); }
__device__ __forceinline__ float ex2(float x) {
    float r;
    asm("v_exp_f32 %0, %1\n\ts_nop 1" : "=v"(r) : "v"(x));
    return r;
}
__device__ __forceinline__ float bcast(float v, int lane) {
    return __int_as_float(__builtin_amdgcn_readlane(__float_as_int(v), lane));
}
__device__ __forceinline__ float xswap(float x) {
    // returned b's LOW lanes hold the high-half value (validated R4..R7).
    float a = x, b = x;
    asm("s_nop 0\n\tv_permlane32_swap_b32 %0, %1\n\ts_nop 0"
        : "+v"(a), "+v"(b));
    return b;
}
__device__ __forceinline__ unsigned short f2bf(float f) {   // RNE fp32->bf16
    unsigned u = __float_as_uint(f);
    return (unsigned short)((u + 0x7FFFu + ((u >> 16) & 1u)) >> 16);
}

// gate column map: n<50: unit n>>1, gate i (even) / g (odd);
//                  n>=50: m=n-50, unit m>>1, gate f (even) / o (odd).
__device__ __forceinline__ void colmap(int n, int& g, float& scl) {
    if (n < 50) {
        const int r = n >> 1;
        g = ((n & 1) ? 2 : 0) * Hn + r;
        scl = (n & 1) ? SCL_T : SCL_S;
    } else {
        const int m = n - 50, r = m >> 1;
        g = ((m & 1) ? 3 : 1) * Hn + r;
        scl = SCL_S;
    }
}

// =====================  the single fused kernel  =========================
__global__ __launch_bounds__(192, 1)
void lstm_fused(const float* __restrict__ x, const float* __restrict__ W_ih,
                const float* __restrict__ W_hh, const float* __restrict__ b_ih,
                const float* __restrict__ b_hh, const float* __restrict__ W_fc,
                const float* __restrict__ b_fc, float* __restrict__ out) {
    __shared__ short lB[112 * 72];     // W_ih permuted+scaled bf16
    __shared__ float lbias[112];       // (b_ih+b_hh) permuted+scaled
    __shared__ short xlds[16 * 72];    // x chunk as bf16, k1 frag layout
    __shared__ float gbuf[2][800];     // gates for 8 steps, double-buffered
    __shared__ float hbuf[16][64];     // h ring for FC wave

    const int tid  = threadIdx.x;
    const int wid  = tid >> 6;
    const int lane = tid & 63;
    const int b    = blockIdx.x;

    // ---- cooperative staging: W_ih -> lB (bf16, colmap+scale), bias ----
    for (int i = tid; i < 112 * 64; i += 192) {
        const int n = i >> 6, k = i & 63;
        float v = 0.f;
        if (n < Gn) {
            int g; float scl;
            colmap(n, g, scl);
            v = W_ih[(size_t)g * In + k] * scl;
        }
        lB[n * 72 + k] = (short)f2bf(v);
    }
    if (tid < 112) {
        float v = 0.f;
        if (tid < Gn) {
            int g; float scl;
            colmap(tid, g, scl);
            v = (b_ih[g] + b_hh[g]) * scl;
        }
        lbias[tid] = v;
    }
    for (int i = tid; i < 16 * 72; i += 192) xlds[i] = 0;   // junk rows = 0
    __syncthreads();

    // ---- per-wave state ----
    float wAv[25], wBv[25];          // wave0
    float c = 0.f, h = 0.f;
    float sB = 1.f, dB = 0.f;
    int coff = 0;
    float wFC[25];                   // wave1
    float bfc = 0.f;
    float* op = nullptr;
    short8 bf0[7], bf1[7];           // wave2: resident B fragments
    float biasv[7];
    float4 xra, xrb;                 // wave2: x prefetch regs (next chunk)
    const float* xb = x + (size_t)b * Tn * In;

    const int quad = lane >> 4;
    const int l16  = lane & 15;

    if (wid == 0) {
        const bool lo = lane < 32;
        const int rr  = min(lane & 31, Hn - 1);
        const float sclA = SCL_S;
        const float sclB = lo ? SCL_T : SCL_S;
        sB = lo ? 2.f : 1.f;
        dB = lo ? -1.f : 0.f;
        const float* rowA = W_hh + (size_t)((lo ? 0 : 1) * Hn + rr) * Hn;
        const float* rowB = W_hh + (size_t)((lo ? 2 : 3) * Hn + rr) * Hn;
#pragma unroll
        for (int j = 0; j < 25; ++j) {
            wAv[j] = rowA[j] * sclA;
            wBv[j] = rowB[j] * sclB;
        }
        coff = 2 * rr + (lo ? 0 : 50);
    } else if (wid == 1) {
#pragma unroll
        for (int j = 0; j < 25; ++j) wFC[j] = W_fc[(size_t)lane * Hn + j];
        bfc = b_fc[lane];
        op = out + (size_t)b * Tn * On + lane;
    } else {
        // resident B fragments + bias
#pragma unroll
        for (int nt = 0; nt < 7; ++nt) {
            const int col = nt * 16 + l16;
            bf0[nt] = *(const short8*)&lB[col * 72 + 0  + quad * 8];
            bf1[nt] = *(const short8*)&lB[col * 72 + 32 + quad * 8];
            biasv[nt] = lbias[col];
        }
        // load x chunk 0 and write to xlds (bf16, k1 fragment layout)
        {
            const float4 a = *(const float4*)(xb + lane * 8);
            const float4 d = *(const float4*)(xb + lane * 8 + 4);
            i32x4 p;
            p.x = (int)(((unsigned)f2bf(a.y) << 16) | f2bf(a.x));
            p.y = (int)(((unsigned)f2bf(a.w) << 16) | f2bf(a.z));
            p.z = (int)(((unsigned)f2bf(d.y) << 16) | f2bf(d.x));
            p.w = (int)(((unsigned)f2bf(d.w) << 16) | f2bf(d.z));
            *(i32x4*)&xlds[(lane >> 3) * 72 + (lane & 7) * 8] = p;
        }
    }
    // full-drain one-time handoff (defensive: R9 hardening)
    __syncthreads();

    if (wid == 2) {
        // produce chunk 0 into gbuf[0]
        const short8 a0 = *(const short8*)&xlds[l16 * 72 + 0  + quad * 8];
        const short8 a1 = *(const short8*)&xlds[l16 * 72 + 32 + quad * 8];
#pragma unroll
        for (int nt = 0; nt < 7; ++nt) {
            f32x4 acc = {biasv[nt], biasv[nt], biasv[nt], biasv[nt]};
            acc = __builtin_amdgcn_mfma_f32_16x16x32_bf16(a0, bf0[nt], acc, 0, 0, 0);
            acc = __builtin_amdgcn_mfma_f32_16x16x32_bf16(a1, bf1[nt], acc, 0, 0, 0);
            const int col = nt * 16 + l16;
            if (lane < 32 && col < Gn) {
#pragma unroll
                for (int i = 0; i < 4; ++i)
                    gbuf[0][(quad * 4 + i) * 100 + col] = acc[i];
            }
        }
        // prefetch x for chunk 1
        xra = *(const float4*)(xb + 512 + lane * 8);
        xrb = *(const float4*)(xb + 512 + lane * 8 + 4);
    }
    __syncthreads();   // chunk 0 visible to wave0

    // =========================== main loop ==============================
#pragma unroll 1
    for (int k = 0; k < 129; ++k) {
        if (wid == 0) {
            if (k < 128) {
                const int kb = k & 1;
                float2 g[8];
#pragma unroll
                for (int s = 0; s < 8; ++s)
                    g[s] = *(const float2*)&gbuf[kb][s * 100 + coff];
#pragma unroll
                for (int s = 0; s < 8; ++s) {
                    const int t = k * 8 + s;
                    float aA0 = g[s].x, aB0 = g[s].y;
                    float aA1 = 0.f,   aB1 = 0.f;
#pragma unroll
                    for (int j = 0; j < 24; j += 2) {
                        const float h0 = bcast(h, j);
                        const float h1 = bcast(h, j + 1);
                        aA0 = fmaf(wAv[j],     h0, aA0);
                        aB0 = fmaf(wBv[j],     h0, aB0);
                        aA1 = fmaf(wAv[j + 1], h1, aA1);
                        aB1 = fmaf(wBv[j + 1], h1, aB1);
                    }
                    {
                        const float h0 = bcast(h, 24);
                        aA0 = fmaf(wAv[24], h0, aA0);
                        aB0 = fmaf(wBv[24], h0, aB0);
                    }
                    const float aA = aA0 + aA1;
                    const float aB = aB0 + aB1;

                    const float actA = frcp(1.f + ex2(aA));            // I / F
                    const float actB = sB * frcp(1.f + ex2(aB)) + dB;  // G / O
                    const float Fg = xswap(actA);
                    const float Og = xswap(actB);
                    c = Fg * c + actA * actB;                // valid lanes 0..24
                    const float th = 2.f * frcp(1.f + ex2(c * SCL_T)) - 1.f;
                    h = Og * th;

                    hbuf[t & 15][lane] = h;                  // junk in lanes 25+
                }
            }
        } else if (wid == 1) {
            if (k >= 1) {
#pragma unroll
                for (int s = 0; s < 8; ++s) {
                    const int t = (k - 1) * 8 + s;
                    const int sl = t & 15;
                    float a0 = bfc, a1 = 0.f;
#pragma unroll
                    for (int j = 0; j < 24; j += 2) {
                        a0 = fmaf(hbuf[sl][j],     wFC[j],     a0);
                        a1 = fmaf(hbuf[sl][j + 1], wFC[j + 1], a1);
                    }
                    a0 = fmaf(hbuf[sl][24], wFC[24], a0);
                    op[(size_t)t * On] = a0 + a1;
                }
            }
        } else {
            if (k < 127) {
                // produce chunk k+1 from prefetched regs (vmcnt auto-wait)
                i32x4 p;
                p.x = (int)(((unsigned)f2bf(xra.y) << 16) | f2bf(xra.x));
                p.y = (int)(((unsigned)f2bf(xra.w) << 16) | f2bf(xra.z));
                p.z = (int)(((unsigned)f2bf(xrb.y) << 16) | f2bf(xrb.x));
                p.w = (int)(((unsigned)f2bf(xrb.w) << 16) | f2bf(xrb.z));
                *(i32x4*)&xlds[(lane >> 3) * 72 + (lane & 7) * 8] = p;
                // prefetch x for chunk k+2 (consumed next iteration)
                if (k < 126) {
                    const float* xs = xb + (size_t)(k + 2) * 512;
                    xra = *(const float4*)(xs + lane * 8);
                    xrb = *(const float4*)(xs + lane * 8 + 4);
                }
                asm volatile("s_waitcnt lgkmcnt(0)" ::: "memory");
                const short8 a0 = *(const short8*)&xlds[l16 * 72 + 0  + quad * 8];
                const short8 a1 = *(const short8*)&xlds[l16 * 72 + 32 + quad * 8];
                const int nb = (k + 1) & 1;
#pragma unroll
                for (int nt = 0; nt < 7; ++nt) {
                    f32x4 acc = {biasv[nt], biasv[nt], biasv[nt], biasv[nt]};
                    acc = __builtin_amdgcn_mfma_f32_16x16x32_bf16(a0, bf0[nt], acc, 0, 0, 0);
                    acc = __builtin_amdgcn_mfma_f32_16x16x32_bf16(a1, bf1[nt], acc, 0, 0, 0);
                    const int col = nt * 16 + l16;
                    if (lane < 32 && col < Gn) {
#pragma unroll
                        for (int i = 0; i < 4; ++i)
                            gbuf[nb][(quad * 4 + i) * 100 + col] = acc[i];
                    }
                }
            }
        }
        // raw barrier (R6/R7-proven): drain LDS only; x prefetch in flight
        asm volatile("s_waitcnt lgkmcnt(0)" ::: "memory");
        __builtin_amdgcn_s_barrier();
        asm volatile("" ::: "memory");
    }
}

extern "C" void kernel_launch(void* const* d_in, const int* in_sizes, int n_in,
                              void* d_out, int out_size, void* d_ws, size_t ws_size,
                              hipStream_t stream) {
    const float* x    = (const float*)d_in[0];
    const float* W_ih = (const float*)d_in[1];
    const float* W_hh = (const float*)d_in[2];
    const float* b_ih = (const float*)d_in[3];
    const float* b_hh = (const float*)d_in[4];
    const float* W_fc = (const float*)d_in[5];
    const float* b_fc = (const float*)d_in[6];
    float* out = (float*)d_out;

    lstm_fused<<<Bn, 192, 0, stream>>>(x, W_ih, W_hh, b_ih, b_hh,
                                       W_fc, b_fc, out);
}